// Round 18
// baseline (107.937 us; speedup 1.0000x reference)
//
#include <hip/hip_runtime.h>

typedef unsigned short u16;
typedef unsigned int u32;
typedef __attribute__((ext_vector_type(8))) short bf16x8;
typedef __attribute__((ext_vector_type(4))) float f32x4;
typedef __attribute__((ext_vector_type(16))) float f32x16;

#define LOG2E 1.4426950408889634f
#define QSCALE (0.125f * LOG2E)

__device__ __forceinline__ u16 f2bf(float f) {
  union { float f; u32 u; } x; x.f = f;
  u32 r = x.u + 0x7fffu + ((x.u >> 16) & 1u);   // RNE; inputs are finite
  return (u16)(r >> 16);
}

__device__ __forceinline__ u32 cvtpk(float a, float b) {
  u32 r;
  asm("v_cvt_pk_bf16_f32 %0, %1, %2" : "=v"(r) : "v"(a), "v"(b));
  return r;
}

__device__ __forceinline__ bf16x8 mkfrag(u32 a, u32 b, u32 c, u32 d) {
  union { u32 w[4]; bf16x8 v; } u;
  u.w[0] = a; u.w[1] = b; u.w[2] = c; u.w[3] = d;
  return u.v;
}

__device__ __forceinline__ void gload_lds16(const void* g, void* l) {
  __builtin_amdgcn_global_load_lds((const __attribute__((address_space(1))) u32*)g,
                                   (__attribute__((address_space(3))) u32*)l, 16, 0, 0);
}

// pack 32 P-values (f32) -> two A-fragments via cvt_pk + lo/hi half exchange (T12)
__device__ __forceinline__ void packP(const f32x16& s, int hi, bf16x8& P0, bf16x8& P1) {
  u32 w0 = cvtpk(s[0], s[1]),  w1 = cvtpk(s[2], s[3]);
  u32 w2 = cvtpk(s[4], s[5]),  w3 = cvtpk(s[6], s[7]);
  u32 w4 = cvtpk(s[8], s[9]),  w5 = cvtpk(s[10], s[11]);
  u32 w6 = cvtpk(s[12], s[13]), w7 = cvtpk(s[14], s[15]);
  u32 x0 = __shfl_xor((int)w0, 32), x1 = __shfl_xor((int)w1, 32);
  u32 x2 = __shfl_xor((int)w2, 32), x3 = __shfl_xor((int)w3, 32);
  u32 x4 = __shfl_xor((int)w4, 32), x5 = __shfl_xor((int)w5, 32);
  u32 x6 = __shfl_xor((int)w6, 32), x7 = __shfl_xor((int)w7, 32);
  P0 = mkfrag(hi ? x2 : w0, hi ? x3 : w1, hi ? w2 : x0, hi ? w3 : x1);
  P1 = mkfrag(hi ? x6 : w4, hi ? x7 : w5, hi ? w6 : x4, hi ? w7 : x5);
}

// ---------------- prep: fp32 -> bf16 (x), 8 elems/thread ----------------
__global__ __launch_bounds__(256) void k_cvt_x(const float* __restrict__ in, u16* __restrict__ out) {
  int i = blockIdx.x * 256 + threadIdx.x;
  const float4* p = (const float4*)in;
  float4 a = p[i * 2], b = p[i * 2 + 1];
  uint4 o;
  o.x = (u32)f2bf(a.x) | ((u32)f2bf(a.y) << 16);
  o.y = (u32)f2bf(a.z) | ((u32)f2bf(a.w) << 16);
  o.z = (u32)f2bf(b.x) | ((u32)f2bf(b.y) << 16);
  o.w = (u32)f2bf(b.z) | ((u32)f2bf(b.w) << 16);
  ((uint4*)out)[i] = o;
}

// ---------------- prep: transpose + convert: src[R][Cc] f32 -> dst[Cc][R] bf16 ----------------
__global__ __launch_bounds__(256) void k_transpose_cvt(const float* __restrict__ src, u16* __restrict__ dst,
                                                       int R, int Cc) {
  __shared__ float tile[32][33];
  int c0 = blockIdx.x * 32, r0 = blockIdx.y * 32;
  int tx = threadIdx.x, ty = threadIdx.y;   // (32,8)
  #pragma unroll
  for (int j = 0; j < 4; ++j)
    tile[ty * 4 + j][tx] = src[(r0 + ty * 4 + j) * Cc + c0 + tx];
  __syncthreads();
  #pragma unroll
  for (int j = 0; j < 4; ++j) {
    int cl = ty * 4 + j;
    dst[(c0 + cl) * R + r0 + tx] = f2bf(tile[tx][cl]);
  }
}

// -------- 128x128 bf16 GEMM (R11 frozen), K=1024, BK=32, 8 waves, depth-2 prefetch, swizzled LDS --
template <int EPI, int NBN>
__global__ __launch_bounds__(512) void k_gemm(const u16* __restrict__ A, const u16* __restrict__ Bt,
                                              const float* __restrict__ bias,
                                              u16* __restrict__ oq, u16* __restrict__ ok,
                                              u16* __restrict__ ovt, float* __restrict__ of) {
  __shared__ u16 lds[24576];
  const int tid = threadIdx.x;
  const int l = tid & 63, w = tid >> 6;
  const int wm = w >> 2, wn = w & 3;
  const int lr = l & 15, lh = l >> 4;
  const int cpx = gridDim.x >> 3;
  const int wg = (blockIdx.x & 7) * cpx + (blockIdx.x >> 3);
  const int bn = wg % NBN, bm = wg / NBN;

  f32x4 acc[4][2] = {};
  const int e = tid * 8;
  const int srow = e >> 5;
  const int sgr  = (e >> 3) & 3;
  const int scol = (sgr ^ ((srow >> 1) & 3)) * 8;
  const u16* gA = A + (bm * 128 + srow) * 1024 + scol;
  const u16* gB = Bt + (bn * 128 + srow) * 1024 + scol;

  #define GSTAGE(kk, b)                                              \
    do {                                                             \
      gload_lds16(gA + (kk), lds + (b) * 8192 + e);                  \
      gload_lds16(gB + (kk), lds + (b) * 8192 + 4096 + e);           \
    } while (0)

  GSTAGE(0, 0);
  GSTAGE(32, 1);
  int cur = 0, nxt = 2;

  for (int it = 0; it < 32; ++it) {
    if (it < 31) asm volatile("s_waitcnt vmcnt(2)" ::: "memory");
    else         asm volatile("s_waitcnt vmcnt(0)" ::: "memory");
    __builtin_amdgcn_s_barrier();
    __builtin_amdgcn_sched_barrier(0);

    if (it < 30) GSTAGE((it + 2) * 32, nxt);

    const u16* Asc = lds + cur * 8192;
    bf16x8 af[4], bfr[2];
    #pragma unroll
    for (int mi = 0; mi < 4; ++mi) {
      int r = wm * 64 + mi * 16 + lr;
      af[mi] = *(const bf16x8*)(Asc + r * 32 + ((lh ^ ((r >> 1) & 3)) * 8));
    }
    #pragma unroll
    for (int ni = 0; ni < 2; ++ni) {
      int r = wn * 32 + ni * 16 + lr;
      bfr[ni] = *(const bf16x8*)(Asc + 4096 + r * 32 + ((lh ^ ((r >> 1) & 3)) * 8));
    }
    #pragma unroll
    for (int mi = 0; mi < 4; ++mi)
      #pragma unroll
      for (int ni = 0; ni < 2; ++ni)
        acc[mi][ni] = __builtin_amdgcn_mfma_f32_16x16x32_bf16(af[mi], bfr[ni], acc[mi][ni], 0, 0, 0);

    cur = (cur == 2) ? 0 : cur + 1;
    nxt = (nxt == 2) ? 0 : nxt + 1;
  }
  #undef GSTAGE

  if (EPI == 0) {
    #pragma unroll
    for (int ni = 0; ni < 2; ++ni) {
      int col = bn * 128 + wn * 32 + ni * 16 + lr;
      float bb = bias[col];
      #pragma unroll
      for (int mi = 0; mi < 4; ++mi) {
        int row = bm * 128 + wm * 64 + mi * 16 + lh * 4;
        #pragma unroll
        for (int r = 0; r < 4; ++r)
          of[(row + r) * (NBN * 128) + col] = acc[mi][ni][r] + bb;
      }
    }
  } else {
    const int s = bn >> 3;                 // third: 0=q, 1=k, 2=v
    __syncthreads();
    if (s < 2) {
      u16* dst = (s == 0) ? oq : ok;
      const float sc = (s == 0) ? QSCALE : 1.0f;
      #pragma unroll
      for (int ni = 0; ni < 2; ++ni) {
        int cl = wn * 32 + ni * 16 + lr;
        float bb = bias[bn * 128 + cl];
        #pragma unroll
        for (int mi = 0; mi < 4; ++mi) {
          int rl = wm * 64 + mi * 16 + lh * 4;
          #pragma unroll
          for (int r = 0; r < 4; ++r)
            lds[(rl + r) * 136 + cl] = f2bf((acc[mi][ni][r] + bb) * sc);
        }
      }
      __syncthreads();
      const int row = tid >> 2, q4 = tid & 3;
      const int h0 = ((bn * 128) & 1023) >> 6;
      const int b = (bm * 128) >> 10, n0 = (bm * 128) & 1023;
      const u16* srow2 = lds + row * 136 + q4 * 32;
      u16* drow = dst + ((u32)((b * 16 + h0 + (q4 >> 1)) * 1024) + n0 + row) * 64 + (q4 & 1) * 32;
      #pragma unroll
      for (int j = 0; j < 4; ++j)
        *(uint4*)(drow + j * 8) = *(const uint4*)(srow2 + j * 8);
    } else {
      #pragma unroll
      for (int ni = 0; ni < 2; ++ni) {
        int cl = wn * 32 + ni * 16 + lr;
        float bb = bias[bn * 128 + cl];
        #pragma unroll
        for (int mi = 0; mi < 4; ++mi) {
          int rl = wm * 64 + mi * 16 + lh * 4;
          u32 p0 = (u32)f2bf(acc[mi][ni][0] + bb) | ((u32)f2bf(acc[mi][ni][1] + bb) << 16);
          u32 p1 = (u32)f2bf(acc[mi][ni][2] + bb) | ((u32)f2bf(acc[mi][ni][3] + bb) << 16);
          uint2 pk; pk.x = p0; pk.y = p1;
          *(uint2*)(lds + cl * 136 + rl) = pk;
        }
      }
      __syncthreads();
      const int cl = tid >> 2, q4 = tid & 3;
      const int c = bn * 128 + cl, cc = c & 1023, h = cc >> 6, d = cc & 63;
      const int b = (bm * 128) >> 10, n0 = (bm * 128) & 1023;
      const u16* srow2 = lds + cl * 136 + q4 * 32;
      u16* drow = ovt + ((b * 16 + h) * 64 + d) * 1024 + n0 + q4 * 32;
      #pragma unroll
      for (int j = 0; j < 4; ++j)
        *(uint4*)(drow + j * 8) = *(const uint4*)(srow2 + j * 8);
    }
  }
}

// ======== shared attn machinery (max-free softmax; proven R10 pipeline) ========
#define ATTN_MACROS                                                            \
  const int swz = (lq & 7) << 4;                                               \
  (void)swz;

#define STAGE_DEF(t, kb, vb)                                                   \
    do {                                                                       \
      gload_lds16(kg + (t) * 4096 + r0_ * 64 + s0_ * 8, Ks[kb] + ch0 * 8);     \
      gload_lds16(kg + (t) * 4096 + r1_ * 64 + s1_ * 8, Ks[kb] + ch1 * 8);     \
      gload_lds16(vg + r0_ * 1024 + (t) * 64 + s0_ * 8, Vs[vb] + ch0 * 8);     \
      gload_lds16(vg + r1_ * 1024 + (t) * 64 + s1_ * 8, Vs[vb] + ch1 * 8);     \
    } while (0)

#define QKM_DEF(kb, SA, SB)                                                    \
    do {                                                                       \
      const char* Kb = (const char*)Ks[kb];                                    \
      _Pragma("unroll")                                                        \
      for (int ks2 = 0; ks2 < 4; ++ks2) {                                      \
        bf16x8 kf0 = *(const bf16x8*)(Kb + (((lq) * 128 + ks2 * 32 + hi * 16) ^ swz));      \
        bf16x8 kf1 = *(const bf16x8*)(Kb + (((32 + lq) * 128 + ks2 * 32 + hi * 16) ^ swz)); \
        SA = __builtin_amdgcn_mfma_f32_32x32x16_bf16(kf0, qf[ks2], SA, 0, 0, 0); \
        SB = __builtin_amdgcn_mfma_f32_32x32x16_bf16(kf1, qf[ks2], SB, 0, 0, 0); \
      }                                                                        \
    } while (0)

#define SM_DEF(SA, SB)                                                         \
    do {                                                                       \
      float l0 = 0.f, l1 = 0.f, l2 = 0.f, l3 = 0.f;                            \
      _Pragma("unroll") for (int r = 0; r < 16; r += 4) {                      \
        float e0 = __builtin_amdgcn_exp2f(SA[r]);                              \
        float e1 = __builtin_amdgcn_exp2f(SA[r + 1]);                          \
        float e2 = __builtin_amdgcn_exp2f(SA[r + 2]);                          \
        float e3 = __builtin_amdgcn_exp2f(SA[r + 3]);                          \
        SA[r] = e0; SA[r + 1] = e1; SA[r + 2] = e2; SA[r + 3] = e3;            \
        l0 += e0; l1 += e1; l2 += e2; l3 += e3;                                \
      }                                                                        \
      _Pragma("unroll") for (int r = 0; r < 16; r += 4) {                      \
        float e0 = __builtin_amdgcn_exp2f(SB[r]);                              \
        float e1 = __builtin_amdgcn_exp2f(SB[r + 1]);                          \
        float e2 = __builtin_amdgcn_exp2f(SB[r + 2]);                          \
        float e3 = __builtin_amdgcn_exp2f(SB[r + 3]);                          \
        SB[r] = e0; SB[r + 1] = e1; SB[r + 2] = e2; SB[r + 3] = e3;            \
        l0 += e0; l1 += e1; l2 += e2; l3 += e3;                                \
      }                                                                        \
      lsum += (l0 + l1) + (l2 + l3);                                           \
      packP(SA, hi, pa[0], pa[1]);                                             \
      packP(SB, hi, pa[2], pa[3]);                                             \
    } while (0)

#define PVM_DEF(vb)                                                            \
    do {                                                                       \
      const char* Vb = (const char*)Vs[vb];                                    \
      _Pragma("unroll")                                                        \
      for (int ks2 = 0; ks2 < 4; ++ks2) {                                      \
        bf16x8 vf0 = *(const bf16x8*)(Vb + (((lq) * 128 + ks2 * 32 + hi * 16) ^ swz));      \
        bf16x8 vf1 = *(const bf16x8*)(Vb + (((32 + lq) * 128 + ks2 * 32 + hi * 16) ^ swz)); \
        o0 = __builtin_amdgcn_mfma_f32_32x32x16_bf16(pa[ks2], vf0, o0, 0, 0, 0); \
        o1 = __builtin_amdgcn_mfma_f32_32x32x16_bf16(pa[ks2], vf1, o1, 0, 0, 0); \
      }                                                                        \
    } while (0)

// ---------------- flash attention (fallback, full 16 tiles; R10 best-measured) ----------------
__global__ __launch_bounds__(256) void k_attn(const u16* __restrict__ q, const u16* __restrict__ k,
                                              const u16* __restrict__ vt, u16* __restrict__ ao) {
  __shared__ u16 Ks[2][4096], Vs[3][4096];
  const int tid = threadIdx.x, l = tid & 63, w = tid >> 6;
  const int lq = l & 31, hi = l >> 5;
  const int i = blockIdx.x;
  const int bh = (i & 7) * 8 + ((i >> 3) & 7);
  const int qb = i >> 6;

  const int qrow = qb * 128 + w * 32 + lq;
  const u16* qg = q + bh * 65536 + qrow * 64;
  bf16x8 qf[4];
  #pragma unroll
  for (int ks = 0; ks < 4; ++ks)
    qf[ks] = *(const bf16x8*)(qg + ks * 16 + hi * 8);

  float lsum = 0.f;
  f32x16 o0 = {}, o1 = {};
  bf16x8 pa[4];

  const u16* kg = k + bh * 65536;
  const u16* vg = vt + bh * 65536;

  const int ch0 = tid, ch1 = 256 + tid;
  const int r0_ = ch0 >> 3, s0_ = (ch0 & 7) ^ (r0_ & 7);
  const int r1_ = ch1 >> 3, s1_ = (ch1 & 7) ^ (r1_ & 7);

  const int swz = (lq & 7) << 4;

  STAGE_DEF(0, 0, 0);
  STAGE_DEF(1, 1, 1);

  asm volatile("s_waitcnt vmcnt(6)" ::: "memory");
  __builtin_amdgcn_s_barrier();
  __builtin_amdgcn_sched_barrier(0);
  {
    f32x16 sA = {}, sB = {};
    QKM_DEF(0, sA, sB);
    SM_DEF(sA, sB);
  }

  for (int t = 0; t < 15; ++t) {
    const int vb = t % 3;
    const int kb1 = (t + 1) & 1;
    if (t < 14) asm volatile("s_waitcnt vmcnt(2)" ::: "memory");
    else        asm volatile("s_waitcnt vmcnt(0)" ::: "memory");
    __builtin_amdgcn_s_barrier();
    __builtin_amdgcn_sched_barrier(0);
    if (t < 14) STAGE_DEF(t + 2, (t + 2) & 1, (t + 2) % 3);

    f32x16 sA = {}, sB = {};
    __builtin_amdgcn_s_setprio(1);
    PVM_DEF(vb);
    QKM_DEF(kb1, sA, sB);
    __builtin_amdgcn_s_setprio(0);
    SM_DEF(sA, sB);
  }
  PVM_DEF(0);

  lsum += __shfl_xor(lsum, 32);
  const int b = bh >> 4, h = bh & 15;
  u16* aob = ao + (u32)(b * 1024 + qb * 128 + w * 32) * 1024 + h * 64;
  #pragma unroll
  for (int r = 0; r < 16; ++r) {
    int row = (r & 3) + 8 * (r >> 2) + 4 * hi;
    float inv = 1.0f / __shfl(lsum, row, 64);
    aob[row * 1024 + lq]      = f2bf(o0[r] * inv);
    aob[row * 1024 + 32 + lq] = f2bf(o1[r] * inv);
  }
}

// ---- flash attention, CROSS-BLOCK KV-SPLIT x2: grid 1024, each block does 8 of 16 KV tiles ----
// 4 blocks/CU x 4 waves = 16 waves/CU (LDS 4x40KB = 160KB exactly). Max-free softmax makes the
// merge exact: partials share one scale. Epilogue writes unnormalized f32 O + lsum to workspace.
__global__ __launch_bounds__(256) void k_attn_split(const u16* __restrict__ q, const u16* __restrict__ k,
                                                    const u16* __restrict__ vt,
                                                    float* __restrict__ PO, float* __restrict__ LS) {
  __shared__ u16 Ks[2][4096], Vs[3][4096];
  const int tid = threadIdx.x, l = tid & 63, w = tid >> 6;
  const int lq = l & 31, hi = l >> 5;
  const int hf = blockIdx.x >> 9;                // KV half
  const int i = blockIdx.x & 511;
  const int bh = (i & 7) * 8 + ((i >> 3) & 7);   // XCD-grouped bh
  const int qb = i >> 6;
  const int t0 = hf * 8;

  const int qrow = qb * 128 + w * 32 + lq;
  const u16* qg = q + bh * 65536 + qrow * 64;
  bf16x8 qf[4];
  #pragma unroll
  for (int ks = 0; ks < 4; ++ks)
    qf[ks] = *(const bf16x8*)(qg + ks * 16 + hi * 8);

  float lsum = 0.f;
  f32x16 o0 = {}, o1 = {};
  bf16x8 pa[4];

  const u16* kg = k + bh * 65536;
  const u16* vg = vt + bh * 65536;

  const int ch0 = tid, ch1 = 256 + tid;
  const int r0_ = ch0 >> 3, s0_ = (ch0 & 7) ^ (r0_ & 7);
  const int r1_ = ch1 >> 3, s1_ = (ch1 & 7) ^ (r1_ & 7);

  const int swz = (lq & 7) << 4;

  STAGE_DEF(t0, 0, 0);
  STAGE_DEF(t0 + 1, 1, 1);

  asm volatile("s_waitcnt vmcnt(6)" ::: "memory");   // my K(t0) chunks landed (qf loads older)
  __builtin_amdgcn_s_barrier();
  __builtin_amdgcn_sched_barrier(0);
  {
    f32x16 sA = {}, sB = {};
    QKM_DEF(0, sA, sB);
    SM_DEF(sA, sB);
  }

  for (int tl = 0; tl < 7; ++tl) {
    const int vb = tl % 3;
    const int kb1 = (tl + 1) & 1;
    if (tl < 6) asm volatile("s_waitcnt vmcnt(2)" ::: "memory");   // V(tl), K(tl+1) landed
    else        asm volatile("s_waitcnt vmcnt(0)" ::: "memory");   // drain V(last)
    __builtin_amdgcn_s_barrier();
    __builtin_amdgcn_sched_barrier(0);
    if (tl < 6) STAGE_DEF(t0 + tl + 2, (tl + 2) & 1, (tl + 2) % 3);

    f32x16 sA = {}, sB = {};
    __builtin_amdgcn_s_setprio(1);
    PVM_DEF(vb);
    QKM_DEF(kb1, sA, sB);
    __builtin_amdgcn_s_setprio(0);
    SM_DEF(sA, sB);
  }
  PVM_DEF(1);                                // tile t0+7: 7 % 3 == 1

  // ---- partial epilogue: unnormalized O (f32) + lsum to workspace ----
  lsum += __shfl_xor(lsum, 32);              // complete over this half's keys for row lq
  float* PO_ = PO + (u32)((hf * 64 + bh) * 1024 + qb * 128 + w * 32) * 64;
  #pragma unroll
  for (int r = 0; r < 16; ++r) {
    int row = (r & 3) + 8 * (r >> 2) + 4 * hi;
    PO_[row * 64 + lq]      = o0[r];
    PO_[row * 64 + 32 + lq] = o1[r];
  }
  if (hi == 0)
    LS[(hf * 64 + bh) * 1024 + qb * 128 + w * 32 + lq] = lsum;
}

// ---- merge the two KV halves: AO = (O0+O1)/(l0+l1), bf16 ----
__global__ __launch_bounds__(256) void k_merge(const float* __restrict__ PO, const float* __restrict__ LS,
                                               u16* __restrict__ ao) {
  int idx = blockIdx.x * 256 + threadIdx.x;        // [64 bh][1024 rows][8 dgroups]
  int dg = idx & 7, row = (idx >> 3) & 1023, bh = idx >> 13;
  const float* p0 = PO + ((u32)(bh * 1024 + row) * 64) + dg * 8;
  const float* p1 = p0 + 4194304;                  // hf stride = 64*1024*64 floats
  float l = LS[bh * 1024 + row] + LS[65536 + bh * 1024 + row];
  float inv = 1.0f / l;
  float4 a0 = *(const float4*)p0, a1 = *(const float4*)(p0 + 4);
  float4 b0 = *(const float4*)p1, b1 = *(const float4*)(p1 + 4);
  uint4 o;
  o.x = (u32)f2bf((a0.x + b0.x) * inv) | ((u32)f2bf((a0.y + b0.y) * inv) << 16);
  o.y = (u32)f2bf((a0.z + b0.z) * inv) | ((u32)f2bf((a0.w + b0.w) * inv) << 16);
  o.z = (u32)f2bf((a1.x + b1.x) * inv) | ((u32)f2bf((a1.y + b1.y) * inv) << 16);
  o.w = (u32)f2bf((a1.z + b1.z) * inv) | ((u32)f2bf((a1.w + b1.w) * inv) << 16);
  int b = bh >> 4, h = bh & 15;
  *(uint4*)(ao + (u32)(b * 1024 + row) * 1024 + h * 64 + dg * 8) = o;
}

// ---------------- launch ----------------
extern "C" void kernel_launch(void* const* d_in, const int* in_sizes, int n_in,
                              void* d_out, int out_size, void* d_ws, size_t ws_size,
                              hipStream_t stream) {
  const float* x      = (const float*)d_in[0];
  const float* w_qkv  = (const float*)d_in[1];
  const float* b_qkv  = (const float*)d_in[2];
  const float* w_proj = (const float*)d_in[3];
  const float* b_proj = (const float*)d_in[4];
  float* out = (float*)d_out;
  char* ws = (char*)d_ws;

  u16* X16   = (u16*)ws;                   //  [4096][1024] bf16 (reused as AO later)
  u16* Wqkv  = (u16*)(ws + 8388608);       //  [3072][1024] bf16
  u16* Wproj = (u16*)(ws + 14680064);      //  [1024][1024] bf16
  u16* Q     = (u16*)(ws + 16777216);      //  [64][1024][64]
  u16* K     = (u16*)(ws + 25165824);      //  [64][1024][64]
  u16* VT    = (u16*)(ws + 33554432);      //  [64][64][1024]
  float* PO  = (float*)(ws + 41943040);    //  [2][64][1024][64] f32 partial O (33.5 MB)
  float* LS  = (float*)(ws + 75497472);    //  [2][64][1024] f32 partial lsum (0.5 MB)
  u16* AO    = X16;

  k_cvt_x<<<dim3(2048), dim3(256), 0, stream>>>(x, X16);
  k_transpose_cvt<<<dim3(96, 32), dim3(32, 8), 0, stream>>>(w_qkv, Wqkv, 1024, 3072);
  k_transpose_cvt<<<dim3(32, 32), dim3(32, 8), 0, stream>>>(w_proj, Wproj, 1024, 1024);
  k_gemm<1, 24><<<dim3(768), dim3(512), 0, stream>>>(X16, Wqkv, b_qkv, Q, K, VT, (float*)0);
  if (ws_size >= 76021760) {
    k_attn_split<<<dim3(1024), dim3(256), 0, stream>>>(Q, K, VT, PO, LS);
    k_merge<<<dim3(2048), dim3(256), 0, stream>>>(PO, LS, AO);
  } else {
    k_attn<<<dim3(512), dim3(256), 0, stream>>>(Q, K, VT, AO);
  }
  k_gemm<0, 8><<<dim3(256), dim3(512), 0, stream>>>(AO, Wproj, b_proj, (u16*)0, (u16*)0, (u16*)0, out);
}

// Round 19
// 97.288 us; speedup vs baseline: 1.1095x; 1.1095x over previous
//
#include <hip/hip_runtime.h>

typedef unsigned short u16;
typedef unsigned int u32;
typedef __attribute__((ext_vector_type(8))) short bf16x8;
typedef __attribute__((ext_vector_type(4))) float f32x4;
typedef __attribute__((ext_vector_type(16))) float f32x16;

#define LOG2E 1.4426950408889634f
#define QSCALE (0.125f * LOG2E)

__device__ __forceinline__ u16 f2bf(float f) {
  union { float f; u32 u; } x; x.f = f;
  u32 r = x.u + 0x7fffu + ((x.u >> 16) & 1u);   // RNE; inputs are finite
  return (u16)(r >> 16);
}

__device__ __forceinline__ u32 cvtpk(float a, float b) {
  u32 r;
  asm("v_cvt_pk_bf16_f32 %0, %1, %2" : "=v"(r) : "v"(a), "v"(b));
  return r;
}

__device__ __forceinline__ bf16x8 mkfrag(u32 a, u32 b, u32 c, u32 d) {
  union { u32 w[4]; bf16x8 v; } u;
  u.w[0] = a; u.w[1] = b; u.w[2] = c; u.w[3] = d;
  return u.v;
}

__device__ __forceinline__ void gload_lds16(const void* g, void* l) {
  __builtin_amdgcn_global_load_lds((const __attribute__((address_space(1))) u32*)g,
                                   (__attribute__((address_space(3))) u32*)l, 16, 0, 0);
}

// pack 32 P-values (f32) -> two A-fragments via cvt_pk + lo/hi half exchange (T12)
__device__ __forceinline__ void packP(const f32x16& s, int hi, bf16x8& P0, bf16x8& P1) {
  u32 w0 = cvtpk(s[0], s[1]),  w1 = cvtpk(s[2], s[3]);
  u32 w2 = cvtpk(s[4], s[5]),  w3 = cvtpk(s[6], s[7]);
  u32 w4 = cvtpk(s[8], s[9]),  w5 = cvtpk(s[10], s[11]);
  u32 w6 = cvtpk(s[12], s[13]), w7 = cvtpk(s[14], s[15]);
  u32 x0 = __shfl_xor((int)w0, 32), x1 = __shfl_xor((int)w1, 32);
  u32 x2 = __shfl_xor((int)w2, 32), x3 = __shfl_xor((int)w3, 32);
  u32 x4 = __shfl_xor((int)w4, 32), x5 = __shfl_xor((int)w5, 32);
  u32 x6 = __shfl_xor((int)w6, 32), x7 = __shfl_xor((int)w7, 32);
  P0 = mkfrag(hi ? x2 : w0, hi ? x3 : w1, hi ? w2 : x0, hi ? w3 : x1);
  P1 = mkfrag(hi ? x6 : w4, hi ? x7 : w5, hi ? w6 : x4, hi ? w7 : x5);
}

// ---------------- prep: fp32 -> bf16 (x), 8 elems/thread ----------------
__global__ __launch_bounds__(256) void k_cvt_x(const float* __restrict__ in, u16* __restrict__ out) {
  int i = blockIdx.x * 256 + threadIdx.x;
  const float4* p = (const float4*)in;
  float4 a = p[i * 2], b = p[i * 2 + 1];
  uint4 o;
  o.x = (u32)f2bf(a.x) | ((u32)f2bf(a.y) << 16);
  o.y = (u32)f2bf(a.z) | ((u32)f2bf(a.w) << 16);
  o.z = (u32)f2bf(b.x) | ((u32)f2bf(b.y) << 16);
  o.w = (u32)f2bf(b.z) | ((u32)f2bf(b.w) << 16);
  ((uint4*)out)[i] = o;
}

// ---------------- prep: transpose + convert: src[R][Cc] f32 -> dst[Cc][R] bf16 ----------------
__global__ __launch_bounds__(256) void k_transpose_cvt(const float* __restrict__ src, u16* __restrict__ dst,
                                                       int R, int Cc) {
  __shared__ float tile[32][33];
  int c0 = blockIdx.x * 32, r0 = blockIdx.y * 32;
  int tx = threadIdx.x, ty = threadIdx.y;   // (32,8)
  #pragma unroll
  for (int j = 0; j < 4; ++j)
    tile[ty * 4 + j][tx] = src[(r0 + ty * 4 + j) * Cc + c0 + tx];
  __syncthreads();
  #pragma unroll
  for (int j = 0; j < 4; ++j) {
    int cl = ty * 4 + j;
    dst[(c0 + cl) * R + r0 + tx] = f2bf(tile[tx][cl]);
  }
}

// -------- 128x128 bf16 GEMM (R11 frozen), K=1024, BK=32, 8 waves, depth-2 prefetch, swizzled LDS --
// EPI 0: of[m][col] = acc + bias[col]  (fp32, N=NBN*128)
// EPI 1: qkv: cols [0,1024)->q (scaled, [bh][n][64]), [1024,2048)->k, [2048,3072)->vt ([bh][d][n])
template <int EPI, int NBN>
__global__ __launch_bounds__(512) void k_gemm(const u16* __restrict__ A, const u16* __restrict__ Bt,
                                              const float* __restrict__ bias,
                                              u16* __restrict__ oq, u16* __restrict__ ok,
                                              u16* __restrict__ ovt, float* __restrict__ of) {
  __shared__ u16 lds[24576];                 // 3 staging bufs x 16 KB; EPI1 repack reuses 34816 B
  const int tid = threadIdx.x;
  const int l = tid & 63, w = tid >> 6;      // 8 waves
  const int wm = w >> 2, wn = w & 3;         // 2M x 4N; per-wave 64x32 output
  const int lr = l & 15, lh = l >> 4;
  const int cpx = gridDim.x >> 3;
  const int wg = (blockIdx.x & 7) * cpx + (blockIdx.x >> 3);
  const int bn = wg % NBN, bm = wg / NBN;

  f32x4 acc[4][2] = {};
  const int e = tid * 8;
  const int srow = e >> 5;
  const int sgr  = (e >> 3) & 3;
  const int scol = (sgr ^ ((srow >> 1) & 3)) * 8;
  const u16* gA = A + (bm * 128 + srow) * 1024 + scol;
  const u16* gB = Bt + (bn * 128 + srow) * 1024 + scol;

  #define GSTAGE(kk, b)                                              \
    do {                                                             \
      gload_lds16(gA + (kk), lds + (b) * 8192 + e);                  \
      gload_lds16(gB + (kk), lds + (b) * 8192 + 4096 + e);           \
    } while (0)

  GSTAGE(0, 0);
  GSTAGE(32, 1);
  int cur = 0, nxt = 2;

  for (int it = 0; it < 32; ++it) {
    if (it < 31) asm volatile("s_waitcnt vmcnt(2)" ::: "memory");
    else         asm volatile("s_waitcnt vmcnt(0)" ::: "memory");
    __builtin_amdgcn_s_barrier();
    __builtin_amdgcn_sched_barrier(0);

    if (it < 30) GSTAGE((it + 2) * 32, nxt);

    const u16* Asc = lds + cur * 8192;
    bf16x8 af[4], bfr[2];
    #pragma unroll
    for (int mi = 0; mi < 4; ++mi) {
      int r = wm * 64 + mi * 16 + lr;
      af[mi] = *(const bf16x8*)(Asc + r * 32 + ((lh ^ ((r >> 1) & 3)) * 8));
    }
    #pragma unroll
    for (int ni = 0; ni < 2; ++ni) {
      int r = wn * 32 + ni * 16 + lr;
      bfr[ni] = *(const bf16x8*)(Asc + 4096 + r * 32 + ((lh ^ ((r >> 1) & 3)) * 8));
    }
    #pragma unroll
    for (int mi = 0; mi < 4; ++mi)
      #pragma unroll
      for (int ni = 0; ni < 2; ++ni)
        acc[mi][ni] = __builtin_amdgcn_mfma_f32_16x16x32_bf16(af[mi], bfr[ni], acc[mi][ni], 0, 0, 0);

    cur = (cur == 2) ? 0 : cur + 1;
    nxt = (nxt == 2) ? 0 : nxt + 1;
  }
  #undef GSTAGE

  if (EPI == 0) {
    #pragma unroll
    for (int ni = 0; ni < 2; ++ni) {
      int col = bn * 128 + wn * 32 + ni * 16 + lr;
      float bb = bias[col];
      #pragma unroll
      for (int mi = 0; mi < 4; ++mi) {
        int row = bm * 128 + wm * 64 + mi * 16 + lh * 4;
        #pragma unroll
        for (int r = 0; r < 4; ++r)
          of[(row + r) * (NBN * 128) + col] = acc[mi][ni][r] + bb;
      }
    }
  } else {
    const int s = bn >> 3;                 // third: 0=q, 1=k, 2=v
    __syncthreads();
    if (s < 2) {
      u16* dst = (s == 0) ? oq : ok;
      const float sc = (s == 0) ? QSCALE : 1.0f;
      #pragma unroll
      for (int ni = 0; ni < 2; ++ni) {
        int cl = wn * 32 + ni * 16 + lr;
        float bb = bias[bn * 128 + cl];
        #pragma unroll
        for (int mi = 0; mi < 4; ++mi) {
          int rl = wm * 64 + mi * 16 + lh * 4;
          #pragma unroll
          for (int r = 0; r < 4; ++r)
            lds[(rl + r) * 136 + cl] = f2bf((acc[mi][ni][r] + bb) * sc);
        }
      }
      __syncthreads();
      const int row = tid >> 2, q4 = tid & 3;
      const int h0 = ((bn * 128) & 1023) >> 6;
      const int b = (bm * 128) >> 10, n0 = (bm * 128) & 1023;
      const u16* srow2 = lds + row * 136 + q4 * 32;
      u16* drow = dst + ((u32)((b * 16 + h0 + (q4 >> 1)) * 1024) + n0 + row) * 64 + (q4 & 1) * 32;
      #pragma unroll
      for (int j = 0; j < 4; ++j)
        *(uint4*)(drow + j * 8) = *(const uint4*)(srow2 + j * 8);
    } else {
      #pragma unroll
      for (int ni = 0; ni < 2; ++ni) {
        int cl = wn * 32 + ni * 16 + lr;
        float bb = bias[bn * 128 + cl];
        #pragma unroll
        for (int mi = 0; mi < 4; ++mi) {
          int rl = wm * 64 + mi * 16 + lh * 4;
          u32 p0 = (u32)f2bf(acc[mi][ni][0] + bb) | ((u32)f2bf(acc[mi][ni][1] + bb) << 16);
          u32 p1 = (u32)f2bf(acc[mi][ni][2] + bb) | ((u32)f2bf(acc[mi][ni][3] + bb) << 16);
          uint2 pk; pk.x = p0; pk.y = p1;
          *(uint2*)(lds + cl * 136 + rl) = pk;
        }
      }
      __syncthreads();
      const int cl = tid >> 2, q4 = tid & 3;
      const int c = bn * 128 + cl, cc = c & 1023, h = cc >> 6, d = cc & 63;
      const int b = (bm * 128) >> 10, n0 = (bm * 128) & 1023;
      const u16* srow2 = lds + cl * 136 + q4 * 32;
      u16* drow = ovt + ((b * 16 + h) * 64 + d) * 1024 + n0 + q4 * 32;
      #pragma unroll
      for (int j = 0; j < 4; ++j)
        *(uint4*)(drow + j * 8) = *(const uint4*)(srow2 + j * 8);
    }
  }
}

// ---------------- flash attention (R10 best-measured), KVBLK=64, max-free softmax ----------------
// 1 block = (bh, 128-row q-block), 4 waves x 32 q-rows. K dbuf (2), V tbuf (3) = 40 KB.
// Iter t: vmcnt(2) [V(t),K(t+1) landed] -> barrier -> STAGE(t+2) -> PV(t) ; QK(t+1) ; exp/pack(t+1).
// Numerics: s = 0.18*(q.k), |s| <= ~9 -> p = 2^s in [2^-9, 2^9]; common scale cancels in O/lsum.
__global__ __launch_bounds__(256) void k_attn(const u16* __restrict__ q, const u16* __restrict__ k,
                                              const u16* __restrict__ vt, u16* __restrict__ ao) {
  __shared__ u16 Ks[2][4096], Vs[3][4096];   // 16 KB + 24 KB, XOR-swizzled rows
  const int tid = threadIdx.x, l = tid & 63, w = tid >> 6;
  const int lq = l & 31;
  const int hi = l >> 5;
  const int i = blockIdx.x;
  const int bh = (i & 7) * 8 + ((i >> 3) & 7);   // XCD-grouped bh
  const int qb = i >> 6;

  const int qrow = qb * 128 + w * 32 + lq;
  const u16* qg = q + bh * 65536 + qrow * 64;
  bf16x8 qf[4];
  #pragma unroll
  for (int ks = 0; ks < 4; ++ks)
    qf[ks] = *(const bf16x8*)(qg + ks * 16 + hi * 8);

  float lsum = 0.f;
  f32x16 o0 = {}, o1 = {};
  bf16x8 pa[4];                              // P fragments of tile t, carried across iterations

  const u16* kg = k + bh * 65536;
  const u16* vg = vt + bh * 65536;

  const int ch0 = tid, ch1 = 256 + tid;
  const int r0_ = ch0 >> 3, s0_ = (ch0 & 7) ^ (r0_ & 7);
  const int r1_ = ch1 >> 3, s1_ = (ch1 & 7) ^ (r1_ & 7);

  // K loads FIRST: steady-state vmcnt(2) confirms {V(t), K(t+1)} while V(t+1) stays in flight
  #define STAGE(t, kb, vb)                                                     \
    do {                                                                       \
      gload_lds16(kg + (t) * 4096 + r0_ * 64 + s0_ * 8, Ks[kb] + ch0 * 8);     \
      gload_lds16(kg + (t) * 4096 + r1_ * 64 + s1_ * 8, Ks[kb] + ch1 * 8);     \
      gload_lds16(vg + r0_ * 1024 + (t) * 64 + s0_ * 8, Vs[vb] + ch0 * 8);     \
      gload_lds16(vg + r1_ * 1024 + (t) * 64 + s1_ * 8, Vs[vb] + ch1 * 8);     \
    } while (0)

  const int swz = (lq & 7) << 4;

  #define QKM(kb, SA, SB)                                                      \
    do {                                                                       \
      const char* Kb = (const char*)Ks[kb];                                    \
      _Pragma("unroll")                                                        \
      for (int ks2 = 0; ks2 < 4; ++ks2) {                                      \
        bf16x8 kf0 = *(const bf16x8*)(Kb + (((lq) * 128 + ks2 * 32 + hi * 16) ^ swz));      \
        bf16x8 kf1 = *(const bf16x8*)(Kb + (((32 + lq) * 128 + ks2 * 32 + hi * 16) ^ swz)); \
        SA = __builtin_amdgcn_mfma_f32_32x32x16_bf16(kf0, qf[ks2], SA, 0, 0, 0); \
        SB = __builtin_amdgcn_mfma_f32_32x32x16_bf16(kf1, qf[ks2], SB, 0, 0, 0); \
      }                                                                        \
    } while (0)

  // max-free softmax: p = 2^s elementwise; 4-partial tree for lsum; pack to fragments
  #define SM(SA, SB)                                                           \
    do {                                                                       \
      float l0 = 0.f, l1 = 0.f, l2 = 0.f, l3 = 0.f;                            \
      _Pragma("unroll") for (int r = 0; r < 16; r += 4) {                      \
        float e0 = __builtin_amdgcn_exp2f(SA[r]);                              \
        float e1 = __builtin_amdgcn_exp2f(SA[r + 1]);                          \
        float e2 = __builtin_amdgcn_exp2f(SA[r + 2]);                          \
        float e3 = __builtin_amdgcn_exp2f(SA[r + 3]);                          \
        SA[r] = e0; SA[r + 1] = e1; SA[r + 2] = e2; SA[r + 3] = e3;            \
        l0 += e0; l1 += e1; l2 += e2; l3 += e3;                                \
      }                                                                        \
      _Pragma("unroll") for (int r = 0; r < 16; r += 4) {                      \
        float e0 = __builtin_amdgcn_exp2f(SB[r]);                              \
        float e1 = __builtin_amdgcn_exp2f(SB[r + 1]);                          \
        float e2 = __builtin_amdgcn_exp2f(SB[r + 2]);                          \
        float e3 = __builtin_amdgcn_exp2f(SB[r + 3]);                          \
        SB[r] = e0; SB[r + 1] = e1; SB[r + 2] = e2; SB[r + 3] = e3;            \
        l0 += e0; l1 += e1; l2 += e2; l3 += e3;                                \
      }                                                                        \
      lsum += (l0 + l1) + (l2 + l3);                                           \
      packP(SA, hi, pa[0], pa[1]);                                             \
      packP(SB, hi, pa[2], pa[3]);                                             \
    } while (0)

  #define PVM(vb)                                                              \
    do {                                                                       \
      const char* Vb = (const char*)Vs[vb];                                    \
      _Pragma("unroll")                                                        \
      for (int ks2 = 0; ks2 < 4; ++ks2) {                                      \
        bf16x8 vf0 = *(const bf16x8*)(Vb + (((lq) * 128 + ks2 * 32 + hi * 16) ^ swz));      \
        bf16x8 vf1 = *(const bf16x8*)(Vb + (((32 + lq) * 128 + ks2 * 32 + hi * 16) ^ swz)); \
        o0 = __builtin_amdgcn_mfma_f32_32x32x16_bf16(pa[ks2], vf0, o0, 0, 0, 0); \
        o1 = __builtin_amdgcn_mfma_f32_32x32x16_bf16(pa[ks2], vf1, o1, 0, 0, 0); \
      }                                                                        \
    } while (0)

  STAGE(0, 0, 0);
  STAGE(1, 1, 1);

  // prologue: prep tile 0 (QK + exp + pack)
  asm volatile("s_waitcnt vmcnt(6)" ::: "memory");   // my K(0) chunks landed (qf loads are older)
  __builtin_amdgcn_s_barrier();                      // everyone's K(0) landed
  __builtin_amdgcn_sched_barrier(0);
  {
    f32x16 sA = {}, sB = {};
    QKM(0, sA, sB);
    SM(sA, sB);
  }

  for (int t = 0; t < 15; ++t) {
    const int vb = t % 3;
    const int kb1 = (t + 1) & 1;
    if (t < 14) asm volatile("s_waitcnt vmcnt(2)" ::: "memory");   // V(t), K(t+1) landed
    else        asm volatile("s_waitcnt vmcnt(0)" ::: "memory");   // drain V(15)
    __builtin_amdgcn_s_barrier();            // cross-wave: tile data visible; prev readers done
    __builtin_amdgcn_sched_barrier(0);
    if (t < 14) STAGE(t + 2, (t + 2) & 1, (t + 2) % 3);

    f32x16 sA = {}, sB = {};
    __builtin_amdgcn_s_setprio(1);
    PVM(vb);                                 // MFMA: accumulate tile t (pa from prev iter)
    QKM(kb1, sA, sB);                        // MFMA: scores of tile t+1
    __builtin_amdgcn_s_setprio(0);
    SM(sA, sB);                              // VALU/trans: exp+pack t+1, in shadow of MFMAs
  }
  // tail: PV(15); all staging drained at t=14, barrier passed
  PVM(0);                                    // 15 % 3 == 0
  #undef STAGE
  #undef QKM
  #undef SM
  #undef PVM

  // ---- epilogue ----
  lsum += __shfl_xor(lsum, 32);
  const int b = bh >> 4, h = bh & 15;
  u16* aob = ao + (u32)(b * 1024 + qb * 128 + w * 32) * 1024 + h * 64;
  #pragma unroll
  for (int r = 0; r < 16; ++r) {
    int row = (r & 3) + 8 * (r >> 2) + 4 * hi;
    float inv = 1.0f / __shfl(lsum, row, 64);
    aob[row * 1024 + lq]      = f2bf(o0[r] * inv);
    aob[row * 1024 + 32 + lq] = f2bf(o1[r] * inv);
  }
}

// ---------------- launch ----------------
extern "C" void kernel_launch(void* const* d_in, const int* in_sizes, int n_in,
                              void* d_out, int out_size, void* d_ws, size_t ws_size,
                              hipStream_t stream) {
  const float* x      = (const float*)d_in[0];
  const float* w_qkv  = (const float*)d_in[1];
  const float* b_qkv  = (const float*)d_in[2];
  const float* w_proj = (const float*)d_in[3];
  const float* b_proj = (const float*)d_in[4];
  float* out = (float*)d_out;
  char* ws = (char*)d_ws;

  u16* X16   = (u16*)ws;                   //  [4096][1024] bf16 (reused as AO later)
  u16* Wqkv  = (u16*)(ws + 8388608);       //  [3072][1024] bf16
  u16* Wproj = (u16*)(ws + 14680064);      //  [1024][1024] bf16
  u16* Q     = (u16*)(ws + 16777216);      //  [64][1024][64]
  u16* K     = (u16*)(ws + 25165824);      //  [64][1024][64]
  u16* VT    = (u16*)(ws + 33554432);      //  [64][64][1024]
  u16* AO    = X16;

  k_cvt_x<<<dim3(2048), dim3(256), 0, stream>>>(x, X16);
  k_transpose_cvt<<<dim3(96, 32), dim3(32, 8), 0, stream>>>(w_qkv, Wqkv, 1024, 3072);
  k_transpose_cvt<<<dim3(32, 32), dim3(32, 8), 0, stream>>>(w_proj, Wproj, 1024, 1024);
  k_gemm<1, 24><<<dim3(768), dim3(512), 0, stream>>>(X16, Wqkv, b_qkv, Q, K, VT, (float*)0);
  k_attn<<<dim3(512), dim3(256), 0, stream>>>(Q, K, VT, AO);
  k_gemm<0, 8><<<dim3(256), dim3(512), 0, stream>>>(AO, Wproj, b_proj, (u16*)0, (u16*)0, (u16*)0, out);
}